// Round 7
// baseline (507.131 us; speedup 1.0000x reference)
//
#include <hip/hip_runtime.h>
#include <hip/hip_cooperative_groups.h>

namespace cg = cooperative_groups;

#define N_NODES 100000
#define DEG 16
#define IN_F 128
#define OUT_F 64
#define E_EDGES (N_NODES * DEG)
#define NTILES 1563          // ceil(N/64) gemm tiles
#define NQUADS 25000         // N/4 node-quads

typedef __bf16 bf16x8 __attribute__((ext_vector_type(8)));
typedef unsigned short u16x8 __attribute__((ext_vector_type(8)));
typedef float f32x4 __attribute__((ext_vector_type(4)));

union BF8 { u16x8 u; bf16x8 b; };

__device__ inline float lo_bf(unsigned int u) {
    union { unsigned int i; float f; } v; v.i = u << 16; return v.f;
}
__device__ inline float hi_bf(unsigned int u) {
    union { unsigned int i; float f; } v; v.i = u & 0xFFFF0000u; return v.f;
}
__device__ inline unsigned short f2bf(float f) {
    union { float f; unsigned int i; } v; v.f = f;
    return (unsigned short)((v.i + 0x7FFFu + ((v.i >> 16) & 1u)) >> 16);
}
__device__ inline unsigned int packbf(float a, float b) {
    return (unsigned int)f2bf(a) | ((unsigned int)f2bf(b) << 16);
}

// ============ fused cooperative kernel: GEMM -> sync -> AGG -> sync -> OUT ====
__global__ __launch_bounds__(256, 2) void k_fused(
    const float* __restrict__ in, const float* __restrict__ Wh,
    const float* __restrict__ Wl, const int* __restrict__ dst,
    const float* __restrict__ ah, const float* __restrict__ al,
    unsigned int* __restrict__ H, unsigned int* __restrict__ HAGG,
    f32x4* __restrict__ s, float* __restrict__ out)
{
    cg::grid_group grid = cg::this_grid();
    __shared__ unsigned short ldsW[2][64][136];   // 34816 B

    int wv = threadIdx.x >> 6;
    int lane = threadIdx.x & 63;
    int quad = lane >> 4, c = lane & 15;
    int nblk = gridDim.x;

    // ---- stage W^T into LDS (R1-proven layout), once per block ----
    for (int idx = threadIdx.x; idx < IN_F * OUT_F; idx += 256) {
        int k = idx >> 6, n = idx & 63;
        ldsW[0][n][k] = f2bf(Wh[idx]);
        ldsW[1][n][k] = f2bf(Wl[idx]);
    }
    __syncthreads();

    // ================= Phase 1: H[row][n] = pack(bf16(in@Wh), bf16(in@Wl)) ====
    for (int tile = blockIdx.x; tile < NTILES; tile += nblk) {
        int row0 = tile * 64 + wv * 16;
        int mrow = row0 + c;
        int lrow = mrow < N_NODES ? mrow : (N_NODES - 1);

        bf16x8 afrag[4];
        const float* inrow = in + (size_t)lrow * IN_F + quad * 8;
        #pragma unroll
        for (int kb = 0; kb < 4; kb++) {
            f32x4 v0 = *(const f32x4*)(inrow + kb * 32);
            f32x4 v1 = *(const f32x4*)(inrow + kb * 32 + 4);
            bf16x8 a;
            #pragma unroll
            for (int j = 0; j < 4; j++) { a[j] = (__bf16)v0[j]; a[4 + j] = (__bf16)v1[j]; }
            afrag[kb] = a;
        }

        f32x4 acc[2][4];
        #pragma unroll
        for (int m = 0; m < 2; m++)
            #pragma unroll
            for (int t = 0; t < 4; t++) acc[m][t] = (f32x4){0, 0, 0, 0};

        #pragma unroll
        for (int kb = 0; kb < 4; kb++) {
            #pragma unroll
            for (int t = 0; t < 4; t++) {
                int n = t * 16 + c;
                BF8 bh, bl;
                bh.u = *(const u16x8*)&ldsW[0][n][kb * 32 + quad * 8];
                bl.u = *(const u16x8*)&ldsW[1][n][kb * 32 + quad * 8];
                acc[0][t] = __builtin_amdgcn_mfma_f32_16x16x32_bf16(afrag[kb], bh.b, acc[0][t], 0, 0, 0);
                acc[1][t] = __builtin_amdgcn_mfma_f32_16x16x32_bf16(afrag[kb], bl.b, acc[1][t], 0, 0, 0);
            }
        }

        #pragma unroll
        for (int r = 0; r < 4; r++) {
            int row = row0 + quad * 4 + r;
            if (row >= N_NODES) continue;
            size_t base = (size_t)row * OUT_F + c;
            #pragma unroll
            for (int t = 0; t < 4; t++)
                H[base + t * 16] = packbf(acc[0][t][r], acc[1][t][r]);
        }
    }

    __threadfence();          // agent-scope release: L2 writeback (cross-XCD)
    grid.sync();
    __threadfence();          // agent-scope acquire: L2 invalidate (stale lines)

    // ================= Phase 2: HAGG + attention scalars s ====================
    for (int q = blockIdx.x; q < NQUADS; q += nblk) {
        int node = __builtin_amdgcn_readfirstlane(q * 4 + wv);
        const int* dp = dst + node * DEG;   // wave-uniform -> scalar loads

        unsigned int hu = H[(size_t)node * 64 + lane];
        float hh = lo_bf(hu);
        float hl = hi_bf(hu);
        float sh = 16.0f * hh;   // DEG * h[i] (self-loop among the 16 dst)
        float sl = 16.0f * hl;

        #pragma unroll
        for (int half = 0; half < 2; half++) {
            unsigned int u[8];
            #pragma unroll
            for (int t = 0; t < 8; t++) {
                int j = dp[half * 8 + t];                 // SGPR
                u[t] = H[(size_t)j * 64 + lane];          // 8 loads in flight
            }
            #pragma unroll
            for (int t = 0; t < 8; t++) { sh += lo_bf(u[t]); sl -= hi_bf(u[t]); }
        }
        HAGG[(size_t)node * 64 + lane] = packbf(sh, sl);

        float ph = hh * ah[lane];
        float qh = hh * ah[64 + lane];
        float pl = hl * al[lane];
        float ql = hl * al[64 + lane];
        #pragma unroll
        for (int o = 32; o > 0; o >>= 1) {
            ph += __shfl_xor(ph, o);
            qh += __shfl_xor(qh, o);
            pl += __shfl_xor(pl, o);
            ql += __shfl_xor(ql, o);
        }
        if (lane == 0) s[node] = (f32x4){ph, qh, pl, ql};
    }

    __threadfence();
    grid.sync();
    __threadfence();

    // ================= Phase 3: weighted aggregate + relu6 ====================
    for (int q = blockIdx.x; q < NQUADS; q += nblk) {
        int node = __builtin_amdgcn_readfirstlane(q * 4 + wv);
        const int* dp = dst + node * DEG;

        int jl = dp[lane & 15];                   // lane e<16 owns edge e
        f32x4 si = s[node];                       // wave-uniform
        f32x4 sj = s[jl];
        float xh = si.x + sj.y;                   // p_high[i] + q_high[j]
        float xl = si.z + sj.w;
        float lh = xh > 0.0f ? xh : 0.2f * xh;
        float ll = xl > 0.0f ? xl : 0.2f * xl;
        float wh = __expf(-lh);
        float wl = __expf(-ll);
        float rh = wh, rl = wl;                   // rowsum over RAW exp values
        #pragma unroll
        for (int o = 8; o > 0; o >>= 1) { rh += __shfl_xor(rh, o); rl += __shfl_xor(rl, o); }
        float eh = fminf(wh, 6.0f);               // relu6 on weights
        float el = fminf(wl, 6.0f);

        float acc_h = 0.0f, acc_l = 0.0f;
        #pragma unroll
        for (int half = 0; half < 2; half++) {
            unsigned int u[8];
            float weh[8], wel[8];
            #pragma unroll
            for (int t = 0; t < 8; t++) {
                int j = dp[half * 8 + t];                 // SGPR
                u[t] = HAGG[(size_t)j * 64 + lane];       // 8 loads in flight
            }
            #pragma unroll
            for (int t = 0; t < 8; t++) {
                weh[t] = __shfl(eh, half * 8 + t);
                wel[t] = __shfl(el, half * 8 + t);
            }
            #pragma unroll
            for (int t = 0; t < 8; t++) {
                acc_h += weh[t] * lo_bf(u[t]);
                acc_l += wel[t] * hi_bf(u[t]);
            }
        }
        float r = 0.5f * (acc_h / rh + acc_l / rl);
        r = fminf(fmaxf(r, 0.0f), 6.0f);
        out[(size_t)node * 64 + lane] = r;
    }
}

// ============ R4-proven separate kernels (deterministic fallback path) ========
__global__ __launch_bounds__(256) void k_gemm(
    const float* __restrict__ in, const float* __restrict__ Wh,
    const float* __restrict__ Wl, unsigned int* __restrict__ H)
{
    __shared__ unsigned short ldsW[2][64][136];
    for (int idx = threadIdx.x; idx < IN_F * OUT_F; idx += 256) {
        int k = idx >> 6, n = idx & 63;
        ldsW[0][n][k] = f2bf(Wh[idx]);
        ldsW[1][n][k] = f2bf(Wl[idx]);
    }
    __syncthreads();

    int wave = blockIdx.x * 4 + (threadIdx.x >> 6);
    int lane = threadIdx.x & 63;
    int row0 = wave * 16;
    if (row0 >= N_NODES) return;
    int quad = lane >> 4, c = lane & 15;
    int mrow = row0 + c;
    int lrow = mrow < N_NODES ? mrow : (N_NODES - 1);

    bf16x8 afrag[4];
    const float* inrow = in + (size_t)lrow * IN_F + quad * 8;
    #pragma unroll
    for (int kb = 0; kb < 4; kb++) {
        f32x4 v0 = *(const f32x4*)(inrow + kb * 32);
        f32x4 v1 = *(const f32x4*)(inrow + kb * 32 + 4);
        bf16x8 a;
        #pragma unroll
        for (int j = 0; j < 4; j++) { a[j] = (__bf16)v0[j]; a[4 + j] = (__bf16)v1[j]; }
        afrag[kb] = a;
    }

    f32x4 acc[2][4];
    #pragma unroll
    for (int m = 0; m < 2; m++)
        #pragma unroll
        for (int t = 0; t < 4; t++) acc[m][t] = (f32x4){0, 0, 0, 0};

    #pragma unroll
    for (int kb = 0; kb < 4; kb++) {
        #pragma unroll
        for (int t = 0; t < 4; t++) {
            int n = t * 16 + c;
            BF8 bh, bl;
            bh.u = *(const u16x8*)&ldsW[0][n][kb * 32 + quad * 8];
            bl.u = *(const u16x8*)&ldsW[1][n][kb * 32 + quad * 8];
            acc[0][t] = __builtin_amdgcn_mfma_f32_16x16x32_bf16(afrag[kb], bh.b, acc[0][t], 0, 0, 0);
            acc[1][t] = __builtin_amdgcn_mfma_f32_16x16x32_bf16(afrag[kb], bl.b, acc[1][t], 0, 0, 0);
        }
    }

    #pragma unroll
    for (int r = 0; r < 4; r++) {
        int row = row0 + quad * 4 + r;
        if (row >= N_NODES) continue;
        size_t base = (size_t)row * OUT_F + c;
        #pragma unroll
        for (int t = 0; t < 4; t++)
            H[base + t * 16] = packbf(acc[0][t][r], acc[1][t][r]);
    }
}

__global__ __launch_bounds__(256) void k_agg(
    const unsigned int* __restrict__ H, const int* __restrict__ dst,
    const float* __restrict__ ah, const float* __restrict__ al,
    unsigned int* __restrict__ HAGG, f32x4* __restrict__ s)
{
    int lane = threadIdx.x & 63;
    int node = __builtin_amdgcn_readfirstlane(blockIdx.x * 4 + (threadIdx.x >> 6));
    const int* dp = dst + node * DEG;

    unsigned int hu = H[(size_t)node * 64 + lane];
    float hh = lo_bf(hu);
    float hl = hi_bf(hu);
    float sh = 16.0f * hh;
    float sl = 16.0f * hl;

    #pragma unroll
    for (int half = 0; half < 2; half++) {
        unsigned int u[8];
        #pragma unroll
        for (int t = 0; t < 8; t++) {
            int j = dp[half * 8 + t];
            u[t] = H[(size_t)j * 64 + lane];
        }
        #pragma unroll
        for (int t = 0; t < 8; t++) { sh += lo_bf(u[t]); sl -= hi_bf(u[t]); }
    }
    HAGG[(size_t)node * 64 + lane] = packbf(sh, sl);

    float ph = hh * ah[lane];
    float qh = hh * ah[64 + lane];
    float pl = hl * al[lane];
    float ql = hl * al[64 + lane];
    #pragma unroll
    for (int o = 32; o > 0; o >>= 1) {
        ph += __shfl_xor(ph, o);
        qh += __shfl_xor(qh, o);
        pl += __shfl_xor(pl, o);
        ql += __shfl_xor(ql, o);
    }
    if (lane == 0) s[node] = (f32x4){ph, qh, pl, ql};
}

__global__ __launch_bounds__(256) void k_out(
    const unsigned int* __restrict__ HAGG, const int* __restrict__ dst,
    const f32x4* __restrict__ s, float* __restrict__ out)
{
    int lane = threadIdx.x & 63;
    int node = __builtin_amdgcn_readfirstlane(blockIdx.x * 4 + (threadIdx.x >> 6));
    const int* dp = dst + node * DEG;

    int jl = dp[lane & 15];
    f32x4 si = s[node];
    f32x4 sj = s[jl];
    float xh = si.x + sj.y;
    float xl = si.z + sj.w;
    float lh = xh > 0.0f ? xh : 0.2f * xh;
    float ll = xl > 0.0f ? xl : 0.2f * xl;
    float wh = __expf(-lh);
    float wl = __expf(-ll);
    float rh = wh, rl = wl;
    #pragma unroll
    for (int o = 8; o > 0; o >>= 1) { rh += __shfl_xor(rh, o); rl += __shfl_xor(rl, o); }
    float eh = fminf(wh, 6.0f);
    float el = fminf(wl, 6.0f);

    float acc_h = 0.0f, acc_l = 0.0f;
    #pragma unroll
    for (int half = 0; half < 2; half++) {
        unsigned int u[8];
        float weh[8], wel[8];
        #pragma unroll
        for (int t = 0; t < 8; t++) {
            int j = dp[half * 8 + t];
            u[t] = HAGG[(size_t)j * 64 + lane];
        }
        #pragma unroll
        for (int t = 0; t < 8; t++) {
            weh[t] = __shfl(eh, half * 8 + t);
            wel[t] = __shfl(el, half * 8 + t);
        }
        #pragma unroll
        for (int t = 0; t < 8; t++) {
            acc_h += weh[t] * lo_bf(u[t]);
            acc_l += wel[t] * hi_bf(u[t]);
        }
    }
    float r = 0.5f * (acc_h / rh + acc_l / rl);
    r = fminf(fmaxf(r, 0.0f), 6.0f);
    out[(size_t)node * 64 + lane] = r;
}

extern "C" void kernel_launch(void* const* d_in, const int* in_sizes, int n_in,
                              void* d_out, int out_size, void* d_ws, size_t ws_size,
                              hipStream_t stream) {
    const float* input = (const float*)d_in[0];
    const int*   edge  = (const int*)d_in[1];     // [2, E]: src then dst
    const float* Wh    = (const float*)d_in[2];
    const float* Wl    = (const float*)d_in[3];
    const float* ah    = (const float*)d_in[4];
    const float* al    = (const float*)d_in[5];
    float* out = (float*)d_out;

    unsigned int* H    = (unsigned int*)d_ws;                    // 25.6 MB
    unsigned int* HAGG = H + (size_t)N_NODES * 64;               // 25.6 MB
    f32x4* s = (f32x4*)(HAGG + (size_t)N_NODES * 64);            // 1.6 MB

    const int* dstp = edge + E_EDGES;

    // Size cooperative grid from the occupancy API (host-only queries; capture-safe)
    int occ = 0, ncu = 0;
    hipError_t e1 = hipOccupancyMaxActiveBlocksPerMultiprocessor(
        &occ, (const void*)k_fused, 256, 0);
    hipError_t e2 = hipDeviceGetAttribute(&ncu, hipDeviceAttributeMultiprocessorCount, 0);
    bool launched = false;
    if (e1 == hipSuccess && e2 == hipSuccess && occ > 0 && ncu > 0) {
        int blks = occ * ncu;
        if (blks > NTILES) blks = NTILES;   // never need more than the tile count
        void* args[] = {
            (void*)&input, (void*)&Wh, (void*)&Wl, (void*)&dstp,
            (void*)&ah, (void*)&al, (void*)&H, (void*)&HAGG,
            (void*)&s, (void*)&out
        };
        hipError_t le = hipLaunchCooperativeKernel((const void*)k_fused, dim3(blks),
                                                   dim3(256), args, 0, stream);
        launched = (le == hipSuccess);
    }
    if (!launched) {   // deterministic fallback: R4-proven 3-kernel path
        k_gemm<<<1563, 256, 0, stream>>>(input, Wh, Wl, H);
        k_agg<<<NQUADS, 256, 0, stream>>>(H, dstp, ah, al, HAGG, s);
        k_out<<<NQUADS, 256, 0, stream>>>(HAGG, dstp, s, out);
    }
}

// Round 8
// 302.255 us; speedup vs baseline: 1.6778x; 1.6778x over previous
//
#include <hip/hip_runtime.h>

#define N_NODES 100000
#define DEG 16
#define IN_F 128
#define OUT_F 64
#define E_EDGES (N_NODES * DEG)

typedef __bf16 bf16x8 __attribute__((ext_vector_type(8)));
typedef unsigned short u16x8 __attribute__((ext_vector_type(8)));
typedef float f32x4 __attribute__((ext_vector_type(4)));
typedef unsigned int u32x4 __attribute__((ext_vector_type(4)));

union BF8 { u16x8 u; bf16x8 b; };

__device__ inline float lo_bf(unsigned int u) {
    union { unsigned int i; float f; } v; v.i = u << 16; return v.f;
}
__device__ inline float hi_bf(unsigned int u) {
    union { unsigned int i; float f; } v; v.i = u & 0xFFFF0000u; return v.f;
}
__device__ inline unsigned short f2bf(float f) {
    union { float f; unsigned int i; } v; v.f = f;
    return (unsigned short)((v.i + 0x7FFFu + ((v.i >> 16) & 1u)) >> 16);
}
__device__ inline unsigned int packbf(float a, float b) {
    return (unsigned int)f2bf(a) | ((unsigned int)f2bf(b) << 16);
}

// ---------------- Kernel W: build pre-swizzled bf16 W image (R5-proven) ----
__global__ __launch_bounds__(256) void k_wprep(
    const float* __restrict__ Wh, const float* __restrict__ Wl,
    unsigned short* __restrict__ Wimg)
{
    int idx = blockIdx.x * 256 + threadIdx.x;      // 64 blocks -> 16384 threads
    int m = idx >> 13;
    int rem = idx & 8191;
    int k = rem >> 6, n = rem & 63;
    float v = m ? Wl[rem] : Wh[rem];
    Wimg[m * 8704 + n * 136 + k] = f2bf(v);
}

// ---------------- Kernel A: H[row][n] = pack(bf16(in@Wh), bf16(in@Wl)) (R5-proven) ----
__global__ __launch_bounds__(256) void k_gemm(
    const float* __restrict__ in, const unsigned short* __restrict__ Wimg,
    unsigned int* __restrict__ H)
{
    __shared__ __align__(16) unsigned short ldsW[2][64][136];  // 34816 B
    __shared__ __align__(16) unsigned short ldsA[64][136];     // 17408 B

    {
        const u32x4* src = (const u32x4*)Wimg;
        u32x4* dst = (u32x4*)ldsW;
        for (int i = threadIdx.x; i < 2176; i += 256) dst[i] = src[i];
    }

    int row0B = blockIdx.x * 64;
    {
        const f32x4* src = (const f32x4*)(in + (size_t)row0B * IN_F);
        #pragma unroll
        for (int i = 0; i < 8; i++) {
            int c = threadIdx.x + 256 * i;
            int row = c >> 5;
            int kc = (c & 31) * 4;
            int grow = row0B + row;
            f32x4 v = (grow < N_NODES) ? src[c]
                      : *(const f32x4*)(in + (size_t)(N_NODES - 1) * IN_F + kc);
            unsigned int p0 = packbf(v[0], v[1]);
            unsigned int p1 = packbf(v[2], v[3]);
            *(unsigned int*)&ldsA[row][kc]     = p0;
            *(unsigned int*)&ldsA[row][kc + 2] = p1;
        }
    }
    __syncthreads();

    int wv = threadIdx.x >> 6;
    int lane = threadIdx.x & 63;
    int quad = lane >> 4, c = lane & 15;
    int row0 = row0B + wv * 16;

    bf16x8 afrag[4];
    #pragma unroll
    for (int kb = 0; kb < 4; kb++) {
        BF8 a;
        a.u = *(const u16x8*)&ldsA[wv * 16 + c][kb * 32 + quad * 8];
        afrag[kb] = a.b;
    }

    f32x4 acc[2][4];
    #pragma unroll
    for (int m = 0; m < 2; m++)
        #pragma unroll
        for (int t = 0; t < 4; t++) acc[m][t] = (f32x4){0, 0, 0, 0};

    #pragma unroll
    for (int kb = 0; kb < 4; kb++) {
        #pragma unroll
        for (int t = 0; t < 4; t++) {
            int n = t * 16 + c;
            BF8 bh, bl;
            bh.u = *(const u16x8*)&ldsW[0][n][kb * 32 + quad * 8];
            bl.u = *(const u16x8*)&ldsW[1][n][kb * 32 + quad * 8];
            acc[0][t] = __builtin_amdgcn_mfma_f32_16x16x32_bf16(afrag[kb], bh.b, acc[0][t], 0, 0, 0);
            acc[1][t] = __builtin_amdgcn_mfma_f32_16x16x32_bf16(afrag[kb], bl.b, acc[1][t], 0, 0, 0);
        }
    }

    #pragma unroll
    for (int r = 0; r < 4; r++) {
        int row = row0 + quad * 4 + r;
        if (row >= N_NODES) continue;
        size_t base = (size_t)row * OUT_F + c;
        #pragma unroll
        for (int t = 0; t < 4; t++)
            H[base + t * 16] = packbf(acc[0][t][r], acc[1][t][r]);
    }
}

// ---------------- Kernel B: HAGG (feature-grouped store) + attention scalars s ----
// Body R4/R5-proven; only the HAGG store layout changed:
// HAGG_G[(g*N + node)*8 + f] with g=lane>>3, f=lane&7.
__global__ __launch_bounds__(256) void k_agg(
    const unsigned int* __restrict__ H, const int* __restrict__ dst,
    const float* __restrict__ ah, const float* __restrict__ al,
    unsigned int* __restrict__ HAGG_G, f32x4* __restrict__ s)
{
    int lane = threadIdx.x & 63;
    int node = __builtin_amdgcn_readfirstlane(blockIdx.x * 4 + (threadIdx.x >> 6));
    const int* dp = dst + node * DEG;   // wave-uniform -> scalar loads

    unsigned int hu = H[(size_t)node * 64 + lane];
    float hh = lo_bf(hu);
    float hl = hi_bf(hu);
    float sh = 16.0f * hh;   // DEG * h[i] (self-loop among the 16 dst)
    float sl = 16.0f * hl;

    #pragma unroll
    for (int half = 0; half < 2; half++) {
        unsigned int u[8];
        #pragma unroll
        for (int t = 0; t < 8; t++) {
            int j = dp[half * 8 + t];                 // SGPR
            u[t] = H[(size_t)j * 64 + lane];          // 8 loads in flight
        }
        #pragma unroll
        for (int t = 0; t < 8; t++) { sh += lo_bf(u[t]); sl -= hi_bf(u[t]); }
    }
    HAGG_G[((size_t)(lane >> 3) * N_NODES + node) * 8 + (lane & 7)] = packbf(sh, sl);

    float ph = hh * ah[lane];
    float qh = hh * ah[64 + lane];
    float pl = hl * al[lane];
    float ql = hl * al[64 + lane];
    #pragma unroll
    for (int o = 32; o > 0; o >>= 1) {
        ph += __shfl_xor(ph, o);
        qh += __shfl_xor(qh, o);
        pl += __shfl_xor(pl, o);
        ql += __shfl_xor(ql, o);
    }
    if (lane == 0) s[node] = (f32x4){ph, qh, pl, ql};
}

// ---------------- Kernel C: weighted aggregate + relu6, feature-grouped 8-pass ----
// blockIdx g-major: 3.2 MB gather window per pass -> L2-resident (4 MB/XCD).
// wave = 8 nodes x 8 features; each lane owns 2 edges for weight compute.
__global__ __launch_bounds__(256) void k_out8(
    const unsigned int* __restrict__ HAGG_G, const int* __restrict__ dst,
    const f32x4* __restrict__ s, float* __restrict__ out)
{
    int lane = threadIdx.x & 63;
    int wv = threadIdx.x >> 6;
    int g = blockIdx.x / 3125;            // pass id (blocks dispatched g-major)
    int b = blockIdx.x - g * 3125;
    int n = lane >> 3, f = lane & 7;
    int node = b * 32 + wv * 8 + n;

    const unsigned int* base = HAGG_G + (size_t)g * N_NODES * 8 + f;

    // this lane owns edges 2f and 2f+1 of its node
    int2 jj = *(const int2*)&dst[node * DEG + f * 2];
    f32x4 si = s[node];
    f32x4 sj0 = s[jj.x];
    f32x4 sj1 = s[jj.y];
    float xh0 = si.x + sj0.y, xl0 = si.z + sj0.w;
    float xh1 = si.x + sj1.y, xl1 = si.z + sj1.w;
    float lh0 = xh0 > 0.0f ? xh0 : 0.2f * xh0;
    float ll0 = xl0 > 0.0f ? xl0 : 0.2f * xl0;
    float lh1 = xh1 > 0.0f ? xh1 : 0.2f * xh1;
    float ll1 = xl1 > 0.0f ? xl1 : 0.2f * xl1;
    float wh0 = __expf(-lh0), wl0 = __expf(-ll0);
    float wh1 = __expf(-lh1), wl1 = __expf(-ll1);

    float rh = wh0 + wh1, rl = wl0 + wl1;        // rowsum over RAW exp values
    #pragma unroll
    for (int o = 1; o < 8; o <<= 1) { rh += __shfl_xor(rh, o); rl += __shfl_xor(rl, o); }

    float eh0 = fminf(wh0, 6.0f), el0 = fminf(wl0, 6.0f);   // relu6 on weights
    float eh1 = fminf(wh1, 6.0f), el1 = fminf(wl1, 6.0f);

    // broadcast edge targets + weights within the 8-lane group
    int grpbase = lane & 0x38;
    int jt[16]; float weh[16], wel[16];
    #pragma unroll
    for (int t = 0; t < 16; t++) {
        int srcl = grpbase | (t >> 1);
        jt[t]  = __shfl((t & 1) ? jj.y : jj.x, srcl);
        weh[t] = __shfl((t & 1) ? eh1 : eh0, srcl);
        wel[t] = __shfl((t & 1) ? el1 : el0, srcl);
    }

    unsigned int u[16];
    #pragma unroll
    for (int t = 0; t < 16; t++) u[t] = base[(size_t)jt[t] * 8];   // 16 loads in flight

    float acc_h = 0.0f, acc_l = 0.0f;
    #pragma unroll
    for (int t = 0; t < 16; t++) {
        acc_h += weh[t] * lo_bf(u[t]);
        acc_l += wel[t] * hi_bf(u[t]);
    }

    float r = 0.5f * (acc_h / rh + acc_l / rl);
    r = fminf(fmaxf(r, 0.0f), 6.0f);
    out[(size_t)node * 64 + g * 8 + f] = r;
}

extern "C" void kernel_launch(void* const* d_in, const int* in_sizes, int n_in,
                              void* d_out, int out_size, void* d_ws, size_t ws_size,
                              hipStream_t stream) {
    const float* input = (const float*)d_in[0];
    const int*   edge  = (const int*)d_in[1];     // [2, E]: src then dst
    const float* Wh    = (const float*)d_in[2];
    const float* Wl    = (const float*)d_in[3];
    const float* ah    = (const float*)d_in[4];
    const float* al    = (const float*)d_in[5];
    float* out = (float*)d_out;

    unsigned int* H      = (unsigned int*)d_ws;                  // 25.6 MB
    unsigned int* HAGG_G = H + (size_t)N_NODES * 64;             // 25.6 MB, grouped
    f32x4* s = (f32x4*)(HAGG_G + (size_t)N_NODES * 64);          // 1.6 MB
    unsigned short* Wimg = (unsigned short*)(s + N_NODES);       // 34816 B

    const int* dstp = edge + E_EDGES;

    k_wprep<<<64, 256, 0, stream>>>(Wh, Wl, Wimg);
    k_gemm<<<1563, 256, 0, stream>>>(input, Wimg, H);
    k_agg<<<N_NODES / 4, 256, 0, stream>>>(H, dstp, ah, al, HAGG_G, s);
    k_out8<<<25000, 256, 0, stream>>>(HAGG_G, dstp, s, out);
}

// Round 9
// 231.974 us; speedup vs baseline: 2.1862x; 1.3030x over previous
//
#include <hip/hip_runtime.h>

#define N_NODES 100000
#define DEG 16
#define IN_F 128
#define OUT_F 64
#define E_EDGES (N_NODES * DEG)

typedef __bf16 bf16x8 __attribute__((ext_vector_type(8)));
typedef unsigned short u16x8 __attribute__((ext_vector_type(8)));
typedef float f32x4 __attribute__((ext_vector_type(4)));
typedef unsigned int u32x4 __attribute__((ext_vector_type(4)));

union BF8 { u16x8 u; bf16x8 b; };

__device__ inline float lo_bf(unsigned int u) {
    union { unsigned int i; float f; } v; v.i = u << 16; return v.f;
}
__device__ inline float hi_bf(unsigned int u) {
    union { unsigned int i; float f; } v; v.i = u & 0xFFFF0000u; return v.f;
}
__device__ inline unsigned short f2bf(float f) {
    union { float f; unsigned int i; } v; v.f = f;
    return (unsigned short)((v.i + 0x7FFFu + ((v.i >> 16) & 1u)) >> 16);
}
__device__ inline unsigned int packbf(float a, float b) {
    return (unsigned int)f2bf(a) | ((unsigned int)f2bf(b) << 16);
}

// ---------------- Kernel W: build pre-swizzled bf16 W image (R5-proven) ----
__global__ __launch_bounds__(256) void k_wprep(
    const float* __restrict__ Wh, const float* __restrict__ Wl,
    unsigned short* __restrict__ Wimg)
{
    int idx = blockIdx.x * 256 + threadIdx.x;      // 64 blocks -> 16384 threads
    int m = idx >> 13;
    int rem = idx & 8191;
    int k = rem >> 6, n = rem & 63;
    float v = m ? Wl[rem] : Wh[rem];
    Wimg[m * 8704 + n * 136 + k] = f2bf(v);
}

// ---------------- Kernel A: H[row][n] = pack(bf16(in@Wh), bf16(in@Wl)) (R5-proven) ----
__global__ __launch_bounds__(256) void k_gemm(
    const float* __restrict__ in, const unsigned short* __restrict__ Wimg,
    unsigned int* __restrict__ H)
{
    __shared__ __align__(16) unsigned short ldsW[2][64][136];  // 34816 B
    __shared__ __align__(16) unsigned short ldsA[64][136];     // 17408 B

    {
        const u32x4* src = (const u32x4*)Wimg;
        u32x4* dst = (u32x4*)ldsW;
        for (int i = threadIdx.x; i < 2176; i += 256) dst[i] = src[i];
    }

    int row0B = blockIdx.x * 64;
    {
        const f32x4* src = (const f32x4*)(in + (size_t)row0B * IN_F);
        #pragma unroll
        for (int i = 0; i < 8; i++) {
            int c = threadIdx.x + 256 * i;
            int row = c >> 5;
            int kc = (c & 31) * 4;
            int grow = row0B + row;
            f32x4 v = (grow < N_NODES) ? src[c]
                      : *(const f32x4*)(in + (size_t)(N_NODES - 1) * IN_F + kc);
            unsigned int p0 = packbf(v[0], v[1]);
            unsigned int p1 = packbf(v[2], v[3]);
            *(unsigned int*)&ldsA[row][kc]     = p0;
            *(unsigned int*)&ldsA[row][kc + 2] = p1;
        }
    }
    __syncthreads();

    int wv = threadIdx.x >> 6;
    int lane = threadIdx.x & 63;
    int quad = lane >> 4, c = lane & 15;
    int row0 = row0B + wv * 16;

    bf16x8 afrag[4];
    #pragma unroll
    for (int kb = 0; kb < 4; kb++) {
        BF8 a;
        a.u = *(const u16x8*)&ldsA[wv * 16 + c][kb * 32 + quad * 8];
        afrag[kb] = a.b;
    }

    f32x4 acc[2][4];
    #pragma unroll
    for (int m = 0; m < 2; m++)
        #pragma unroll
        for (int t = 0; t < 4; t++) acc[m][t] = (f32x4){0, 0, 0, 0};

    #pragma unroll
    for (int kb = 0; kb < 4; kb++) {
        #pragma unroll
        for (int t = 0; t < 4; t++) {
            int n = t * 16 + c;
            BF8 bh, bl;
            bh.u = *(const u16x8*)&ldsW[0][n][kb * 32 + quad * 8];
            bl.u = *(const u16x8*)&ldsW[1][n][kb * 32 + quad * 8];
            acc[0][t] = __builtin_amdgcn_mfma_f32_16x16x32_bf16(afrag[kb], bh.b, acc[0][t], 0, 0, 0);
            acc[1][t] = __builtin_amdgcn_mfma_f32_16x16x32_bf16(afrag[kb], bl.b, acc[1][t], 0, 0, 0);
        }
    }

    #pragma unroll
    for (int r = 0; r < 4; r++) {
        int row = row0 + quad * 4 + r;
        if (row >= N_NODES) continue;
        size_t base = (size_t)row * OUT_F + c;
        #pragma unroll
        for (int t = 0; t < 4; t++)
            H[base + t * 16] = packbf(acc[0][t][r], acc[1][t][r]);
    }
}

// ---------------- Kernel B: HAGG + attention scalars s (R4/R5-proven, flat layout) ----
__global__ __launch_bounds__(256) void k_agg(
    const unsigned int* __restrict__ H, const int* __restrict__ dst,
    const float* __restrict__ ah, const float* __restrict__ al,
    unsigned int* __restrict__ HAGG, f32x4* __restrict__ s)
{
    int lane = threadIdx.x & 63;
    int node = __builtin_amdgcn_readfirstlane(blockIdx.x * 4 + (threadIdx.x >> 6));
    const int* dp = dst + node * DEG;   // wave-uniform -> scalar loads

    unsigned int hu = H[(size_t)node * 64 + lane];
    float hh = lo_bf(hu);
    float hl = hi_bf(hu);
    float sh = 16.0f * hh;   // DEG * h[i] (self-loop among the 16 dst)
    float sl = 16.0f * hl;

    #pragma unroll
    for (int half = 0; half < 2; half++) {
        unsigned int u[8];
        #pragma unroll
        for (int t = 0; t < 8; t++) {
            int j = dp[half * 8 + t];                 // SGPR
            u[t] = H[(size_t)j * 64 + lane];          // 8 loads in flight
        }
        #pragma unroll
        for (int t = 0; t < 8; t++) { sh += lo_bf(u[t]); sl -= hi_bf(u[t]); }
    }
    HAGG[(size_t)node * 64 + lane] = packbf(sh, sl);

    float ph = hh * ah[lane];
    float qh = hh * ah[64 + lane];
    float pl = hl * al[lane];
    float ql = hl * al[64 + lane];
    #pragma unroll
    for (int o = 32; o > 0; o >>= 1) {
        ph += __shfl_xor(ph, o);
        qh += __shfl_xor(qh, o);
        pl += __shfl_xor(pl, o);
        ql += __shfl_xor(ql, o);
    }
    if (lane == 0) s[node] = (f32x4){ph, qh, pl, ql};
}

// ---------------- Kernel C: weighted aggregate + relu6, dwordx4 gathers ----
// quad q gathers edges 4q..4q+3 as u32x4 (features 4c..4c+3); 4 fat gather
// instructions instead of 16 narrow ones; cross-quad butterfly; quad0 f32x4 store.
__global__ __launch_bounds__(256) void k_out4(
    const unsigned int* __restrict__ HAGG, const int* __restrict__ dst,
    const f32x4* __restrict__ s, float* __restrict__ out)
{
    int lane = threadIdx.x & 63;
    int node = __builtin_amdgcn_readfirstlane(blockIdx.x * 4 + (threadIdx.x >> 6));
    const int* dp = dst + node * DEG;
    int q = lane >> 4, c = lane & 15;

    // per-quad edge rows: lane loads int4 of its quad's 4 edge targets
    int4 jq = *(const int4*)&dp[q * 4];

    // edge weights: identical to R4 (lane e<16 owns edge e; groups duplicate)
    int jl = dp[c];
    f32x4 si = s[node];                       // wave-uniform
    f32x4 sj = s[jl];
    float xh = si.x + sj.y;                   // p_high[i] + q_high[j]
    float xl = si.z + sj.w;
    float lh = xh > 0.0f ? xh : 0.2f * xh;
    float ll = xl > 0.0f ? xl : 0.2f * xl;
    float wh = __expf(-lh);
    float wl = __expf(-ll);
    float rh = wh, rl = wl;                   // rowsum over RAW exp values
    #pragma unroll
    for (int o = 8; o > 0; o >>= 1) { rh += __shfl_xor(rh, o); rl += __shfl_xor(rl, o); }
    float eh = fminf(wh, 6.0f);               // relu6 on weights
    float el = fminf(wl, 6.0f);

    // 4 fat gathers: instruction i covers 4 rows (one per quad), 256 B each
    unsigned int U[4][4];
    const int* jqp = &jq.x;
    #pragma unroll
    for (int i = 0; i < 4; i++)
        *(u32x4*)U[i] = *(const u32x4*)(HAGG + (size_t)jqp[i] * 64 + c * 4);

    float weh[4], wel[4];
    #pragma unroll
    for (int i = 0; i < 4; i++) {
        weh[i] = __shfl(eh, q * 4 + i);       // per-lane-varying src (bpermute)
        wel[i] = __shfl(el, q * 4 + i);
    }

    float ach[4] = {0, 0, 0, 0}, acl[4] = {0, 0, 0, 0};
    #pragma unroll
    for (int i = 0; i < 4; i++)
        #pragma unroll
        for (int d = 0; d < 4; d++) {
            ach[d] += weh[i] * lo_bf(U[i][d]);
            acl[d] += wel[i] * hi_bf(U[i][d]);
        }

    // reduce partial sums across the 4 quads
    #pragma unroll
    for (int o = 16; o <= 32; o <<= 1)
        #pragma unroll
        for (int d = 0; d < 4; d++) {
            ach[d] += __shfl_xor(ach[d], o);
            acl[d] += __shfl_xor(acl[d], o);
        }

    if (q == 0) {
        f32x4 r;
        #pragma unroll
        for (int d = 0; d < 4; d++) {
            float v = 0.5f * (ach[d] / rh + acl[d] / rl);
            r[d] = fminf(fmaxf(v, 0.0f), 6.0f);
        }
        *(f32x4*)&out[(size_t)node * 64 + c * 4] = r;   // 16 lanes x 16 B = full row
    }
}

extern "C" void kernel_launch(void* const* d_in, const int* in_sizes, int n_in,
                              void* d_out, int out_size, void* d_ws, size_t ws_size,
                              hipStream_t stream) {
    const float* input = (const float*)d_in[0];
    const int*   edge  = (const int*)d_in[1];     // [2, E]: src then dst
    const float* Wh    = (const float*)d_in[2];
    const float* Wl    = (const float*)d_in[3];
    const float* ah    = (const float*)d_in[4];
    const float* al    = (const float*)d_in[5];
    float* out = (float*)d_out;

    unsigned int* H    = (unsigned int*)d_ws;                    // 25.6 MB
    unsigned int* HAGG = H + (size_t)N_NODES * 64;               // 25.6 MB
    f32x4* s = (f32x4*)(HAGG + (size_t)N_NODES * 64);            // 1.6 MB
    unsigned short* Wimg = (unsigned short*)(s + N_NODES);       // 34816 B

    const int* dstp = edge + E_EDGES;

    k_wprep<<<64, 256, 0, stream>>>(Wh, Wl, Wimg);
    k_gemm<<<1563, 256, 0, stream>>>(input, Wimg, H);
    k_agg<<<N_NODES / 4, 256, 0, stream>>>(H, dstp, ah, al, HAGG, s);
    k_out4<<<N_NODES / 4, 256, 0, stream>>>(HAGG, dstp, s, out);
}